// Round 2
// baseline (278.100 us; speedup 1.0000x reference)
//
#include <hip/hip_runtime.h>
#include <hip/hip_bf16.h>

// MultiHeadAttention: B=4 H=12 S=2048 D=64 E=768, causal. fp32 in/out, bf16 MFMA compute.
// Stage 0: convert x fp32 -> bf16; transpose+convert weights.
// Stage 1: QKV GEMM  X[8192,768] @ W -> q/k/v [B,H,S,D] bf16 in ws.
// Stage 2: flash attention (causal, online softmax) -> ao [8192,768] bf16.
// Stage 3: out GEMM ao @ Wp + bp -> d_out (fp32).

typedef __attribute__((ext_vector_type(8))) short bf16x8;
typedef __attribute__((ext_vector_type(4))) float f32x4;

// ws offsets in bf16 elements
#define OFF_XB   0            // 8192*768            = 6291456
#define OFF_WT   6291456      // 3 * 12*64*768       = 1769472
#define OFF_WPT  8060928      // 768*768             =  589824
#define OFF_QKV  8650752      // 3 * 4*12*2048*64    = 18874368
#define OFF_AO   27525120     // 8192*768            = 6291456
// total 33816576 elems = 64.5 MB

__device__ inline ushort f2bf(float f) {
  __hip_bfloat16 h = __float2bfloat16(f);
  return *reinterpret_cast<ushort*>(&h);
}

// ---------- fp32 -> bf16 bulk convert (8 elems/thread)
__global__ __launch_bounds__(256) void cvt_bf16(const float* __restrict__ src,
                                                ushort* __restrict__ dst, int n8) {
  int i = blockIdx.x * 256 + threadIdx.x;
  if (i >= n8) return;
  float4 a = *(const float4*)&src[(size_t)i * 8];
  float4 b = *(const float4*)&src[(size_t)i * 8 + 4];
  ushort u[8] = {f2bf(a.x), f2bf(a.y), f2bf(a.z), f2bf(a.w),
                 f2bf(b.x), f2bf(b.y), f2bf(b.z), f2bf(b.w)};
  *(bf16x8*)&dst[(size_t)i * 8] = *(bf16x8*)u;
}

// ---------- tiled 64x64 transpose+convert: src fp32 [mat][Edim][Ddim] -> dst bf16 [mat][Ddim][Edim]
__global__ __launch_bounds__(256) void transpose_w(const float* __restrict__ src,
                                                   ushort* __restrict__ dst,
                                                   int Edim, int Ddim) {
  __shared__ ushort tile[64][130];  // 65-word row stride, conflict-free
  int mat = blockIdx.y;
  int ntd = Ddim >> 6;
  int te = blockIdx.x / ntd, td = blockIdx.x % ntd;
  size_t base = (size_t)mat * Edim * Ddim;
  int t = threadIdx.x;
#pragma unroll
  for (int i = 0; i < 16; i++) {
    int idx = i * 256 + t;
    int r = idx >> 6, c = idx & 63;
    tile[r][c] = f2bf(src[base + (size_t)(te * 64 + r) * Ddim + td * 64 + c]);
  }
  __syncthreads();
#pragma unroll
  for (int i = 0; i < 16; i++) {
    int idx = i * 256 + t;
    int c = idx >> 6, r = idx & 63;
    dst[base + (size_t)(td * 64 + c) * Edim + te * 64 + r] = tile[r][c];
  }
}

// ---------- QKV projection GEMM: X[8192,768] @ (Wt rows d, cols e) -> qkv bf16
// grid: x = 128 (M/64), y = 36 (ty*12 + h). 256 threads = 4 waves, wave w: rows w*16..+15.
__global__ __launch_bounds__(256) void gemm_qkv(const ushort* __restrict__ X,
                                                const ushort* __restrict__ Wt,
                                                ushort* __restrict__ qkv) {
  __shared__ ushort Alds[64 * 40];  // [row 0..63][k 0..31], stride 40 (80B, 16B-aligned)
  __shared__ ushort Blds[64 * 40];  // [d-col 0..63][k 0..31]
  int mb = blockIdx.x, nb = blockIdx.y;
  int t = threadIdx.x, w = t >> 6, lane = t & 63, lo = lane & 15, g = lane >> 4;
  const ushort* Wb = Wt + (size_t)nb * 64 * 768;
  f32x4 acc[4];
#pragma unroll
  for (int n = 0; n < 4; n++) acc[n] = (f32x4){0.f, 0.f, 0.f, 0.f};
  int r = t >> 2, c4 = t & 3;
  for (int e0 = 0; e0 < 768; e0 += 32) {
    *(bf16x8*)&Alds[r * 40 + c4 * 8] =
        *(const bf16x8*)&X[(size_t)(mb * 64 + r) * 768 + e0 + c4 * 8];
    *(bf16x8*)&Blds[r * 40 + c4 * 8] =
        *(const bf16x8*)&Wb[(size_t)r * 768 + e0 + c4 * 8];
    __syncthreads();
    bf16x8 a = *(const bf16x8*)&Alds[(w * 16 + lo) * 40 + g * 8];
#pragma unroll
    for (int n = 0; n < 4; n++) {
      bf16x8 b = *(const bf16x8*)&Blds[(n * 16 + lo) * 40 + g * 8];
      acc[n] = __builtin_amdgcn_mfma_f32_16x16x32_bf16(a, b, acc[n], 0, 0, 0);
    }
    __syncthreads();
  }
  // C/D layout: row = g*4 + rr, col = lo  (m89-verified)
  int ty = nb / 12, h = nb % 12;
#pragma unroll
  for (int n = 0; n < 4; n++) {
    int d = n * 16 + lo;
#pragma unroll
    for (int rr = 0; rr < 4; rr++) {
      int m = mb * 64 + w * 16 + g * 4 + rr;
      int b = m >> 11, s = m & 2047;
      qkv[(size_t)ty * 6291456 + (size_t)(b * 12 + h) * 131072 + (size_t)s * 64 + d] =
          f2bf(acc[n][rr]);
    }
  }
}

// ---------- causal flash attention. grid: x = 32 (q blocks of 64), y = 48 (b*12+h)
__global__ __launch_bounds__(256) void attn_fwd(const ushort* __restrict__ Qg,
                                                const ushort* __restrict__ Kg,
                                                const ushort* __restrict__ Vg,
                                                ushort* __restrict__ ao) {
  __shared__ ushort Klds[32 * 72];    // [t 0..31][d 0..63], stride 72 (144B)
  __shared__ ushort Vt[64 * 40];      // [d 0..63][t 0..31], stride 40
  __shared__ ushort Plds[4][640];     // per wave: [q 0..15][t 0..31], stride 40
  int qb = blockIdx.x, bh = blockIdx.y;
  int t = threadIdx.x, w = t >> 6, lane = t & 63, lo = lane & 15, g = lane >> 4;
  const ushort* Q = Qg + (size_t)bh * 131072;
  const ushort* K = Kg + (size_t)bh * 131072;
  const ushort* V = Vg + (size_t)bh * 131072;
  int q0 = qb * 64;
  int qrow = q0 + w * 16 + lo;
  // Q fragments held in registers for the whole kernel
  bf16x8 qf0 = *(const bf16x8*)&Q[(size_t)qrow * 64 + g * 8];
  bf16x8 qf1 = *(const bf16x8*)&Q[(size_t)qrow * 64 + 32 + g * 8];
  f32x4 oacc[4];
#pragma unroll
  for (int n = 0; n < 4; n++) oacc[n] = (f32x4){0.f, 0.f, 0.f, 0.f};
  float mrun = -1e30f, lrun = 0.f;
  int nkb = (q0 + 64) >> 5;
  int kr = t >> 3, kc = t & 7;
  for (int kb = 0; kb < nkb; kb++) {
    int t0 = kb * 32;
    // stage K [32][64]: 256 x 16B chunks
    *(bf16x8*)&Klds[kr * 72 + kc * 8] =
        *(const bf16x8*)&K[(size_t)(t0 + kr) * 64 + kc * 8];
    // stage V transposed: threads 0..127, each a row-pair x 8 d-values
    if (t < 128) {
      int pr = t >> 3, dc = t & 7;
      bf16x8 va = *(const bf16x8*)&V[(size_t)(t0 + 2 * pr) * 64 + dc * 8];
      bf16x8 vb = *(const bf16x8*)&V[(size_t)(t0 + 2 * pr + 1) * 64 + dc * 8];
#pragma unroll
      for (int i = 0; i < 8; i++) {
        uint val = (uint)(ushort)va[i] | ((uint)(ushort)vb[i] << 16);
        *(uint*)&Vt[(dc * 8 + i) * 40 + 2 * pr] = val;
      }
    }
    __syncthreads();
    if (t0 <= q0 + w * 16 + 15) {   // wave-uniform causal skip
      // S^T = K · Q^T  (swapped operands -> lane owns one q-row's scores)
      f32x4 st0 = (f32x4){0.f, 0.f, 0.f, 0.f};
      f32x4 st1 = (f32x4){0.f, 0.f, 0.f, 0.f};
      bf16x8 kf;
      kf = *(const bf16x8*)&Klds[lo * 72 + g * 8];
      st0 = __builtin_amdgcn_mfma_f32_16x16x32_bf16(kf, qf0, st0, 0, 0, 0);
      kf = *(const bf16x8*)&Klds[lo * 72 + 32 + g * 8];
      st0 = __builtin_amdgcn_mfma_f32_16x16x32_bf16(kf, qf1, st0, 0, 0, 0);
      kf = *(const bf16x8*)&Klds[(16 + lo) * 72 + g * 8];
      st1 = __builtin_amdgcn_mfma_f32_16x16x32_bf16(kf, qf0, st1, 0, 0, 0);
      kf = *(const bf16x8*)&Klds[(16 + lo) * 72 + 32 + g * 8];
      st1 = __builtin_amdgcn_mfma_f32_16x16x32_bf16(kf, qf1, st1, 0, 0, 0);
      // lane holds S[q = qrow][t = t0 + ct*16 + g*4 + rr]
      float pv[8];
      float mtile = -1e30f;
#pragma unroll
      for (int ct = 0; ct < 2; ct++) {
        f32x4 stv = ct ? st1 : st0;
#pragma unroll
        for (int rr = 0; rr < 4; rr++) {
          int tg = t0 + ct * 16 + g * 4 + rr;
          float s = stv[rr] * 0.125f;
          s = (tg <= qrow) ? s : -1e30f;
          pv[ct * 4 + rr] = s;
          mtile = fmaxf(mtile, s);
        }
      }
      mtile = fmaxf(mtile, __shfl_xor(mtile, 16));
      mtile = fmaxf(mtile, __shfl_xor(mtile, 32));
      float mnew = fmaxf(mrun, mtile);
      float sf = __expf(mrun - mnew);
      float tsum = 0.f;
#pragma unroll
      for (int i = 0; i < 8; i++) { pv[i] = __expf(pv[i] - mnew); tsum += pv[i]; }
      tsum += __shfl_xor(tsum, 16);
      tsum += __shfl_xor(tsum, 32);
      lrun = lrun * sf + tsum;
      mrun = mnew;
      // P -> bf16 -> per-wave LDS ([q][t], t-contiguous 4-packs)
#pragma unroll
      for (int ct = 0; ct < 2; ct++) {
        ushort4 pb;
        pb.x = f2bf(pv[ct * 4 + 0]);
        pb.y = f2bf(pv[ct * 4 + 1]);
        pb.z = f2bf(pv[ct * 4 + 2]);
        pb.w = f2bf(pv[ct * 4 + 3]);
        *(ushort4*)&Plds[w][lo * 40 + ct * 16 + g * 4] = pb;
      }
      // rescale O accumulators (O row = g*4 + rr; sf lives at lane lo == row)
#pragma unroll
      for (int rr = 0; rr < 4; rr++) {
        float sfr = __shfl(sf, g * 4 + rr);
#pragma unroll
        for (int n = 0; n < 4; n++) oacc[n][rr] *= sfr;
      }
      // same-wave LDS RAW fence (rule #18: waitcnt + sched_barrier)
      asm volatile("s_waitcnt lgkmcnt(0)" ::: "memory");
      __builtin_amdgcn_sched_barrier(0);
      bf16x8 pf = *(const bf16x8*)&Plds[w][lo * 40 + g * 8];
#pragma unroll
      for (int n = 0; n < 4; n++) {
        bf16x8 vf = *(const bf16x8*)&Vt[(n * 16 + lo) * 40 + g * 8];
        oacc[n] = __builtin_amdgcn_mfma_f32_16x16x32_bf16(pf, vf, oacc[n], 0, 0, 0);
      }
    }
    __syncthreads();
  }
  // epilogue: normalize by l and write [B,S,H*D] bf16
  float linv[4];
#pragma unroll
  for (int rr = 0; rr < 4; rr++) linv[rr] = 1.f / __shfl(lrun, g * 4 + rr);
  int hh = bh % 12, b = bh / 12;
#pragma unroll
  for (int n = 0; n < 4; n++) {
    int d = n * 16 + lo;
#pragma unroll
    for (int rr = 0; rr < 4; rr++) {
      int m = q0 + w * 16 + g * 4 + rr;
      ao[(size_t)(b * 2048 + m) * 768 + hh * 64 + d] = f2bf(oacc[n][rr] * linv[rr]);
    }
  }
}

// ---------- output projection: ao[8192,768] @ Wp[768,768] + bp -> out fp32
// grid: x = 128, y = 12
__global__ __launch_bounds__(256) void gemm_out(const ushort* __restrict__ A,
                                                const ushort* __restrict__ Bt,
                                                const float* __restrict__ bias,
                                                float* __restrict__ out) {
  __shared__ ushort Alds[64 * 40];
  __shared__ ushort Blds[64 * 40];
  int mb = blockIdx.x, nb = blockIdx.y;
  int t = threadIdx.x, w = t >> 6, lane = t & 63, lo = lane & 15, g = lane >> 4;
  const ushort* Bb = Bt + (size_t)nb * 64 * 768;
  f32x4 acc[4];
#pragma unroll
  for (int n = 0; n < 4; n++) acc[n] = (f32x4){0.f, 0.f, 0.f, 0.f};
  int r = t >> 2, c4 = t & 3;
  for (int e0 = 0; e0 < 768; e0 += 32) {
    *(bf16x8*)&Alds[r * 40 + c4 * 8] =
        *(const bf16x8*)&A[(size_t)(mb * 64 + r) * 768 + e0 + c4 * 8];
    *(bf16x8*)&Blds[r * 40 + c4 * 8] =
        *(const bf16x8*)&Bb[(size_t)r * 768 + e0 + c4 * 8];
    __syncthreads();
    bf16x8 a = *(const bf16x8*)&Alds[(w * 16 + lo) * 40 + g * 8];
#pragma unroll
    for (int n = 0; n < 4; n++) {
      bf16x8 b = *(const bf16x8*)&Blds[(n * 16 + lo) * 40 + g * 8];
      acc[n] = __builtin_amdgcn_mfma_f32_16x16x32_bf16(a, b, acc[n], 0, 0, 0);
    }
    __syncthreads();
  }
#pragma unroll
  for (int n = 0; n < 4; n++) {
    int col = nb * 64 + n * 16 + lo;
    float bv = bias[col];
#pragma unroll
    for (int rr = 0; rr < 4; rr++) {
      int m = mb * 64 + w * 16 + g * 4 + rr;
      out[(size_t)m * 768 + col] = acc[n][rr] + bv;
    }
  }
}

extern "C" void kernel_launch(void* const* d_in, const int* in_sizes, int n_in,
                              void* d_out, int out_size, void* d_ws, size_t ws_size,
                              hipStream_t stream) {
  const float* x  = (const float*)d_in[0];
  const float* Wq = (const float*)d_in[1];
  const float* Wk = (const float*)d_in[2];
  const float* Wv = (const float*)d_in[3];
  const float* Wp = (const float*)d_in[4];
  const float* bp = (const float*)d_in[5];
  float* out = (float*)d_out;
  ushort* ws = (ushort*)d_ws;

  ushort* xb  = ws + OFF_XB;    // [8192][768] bf16
  ushort* wt  = ws + OFF_WT;    // [3][12][64][768] bf16
  ushort* wpt = ws + OFF_WPT;   // [768][768] bf16
  ushort* qkv = ws + OFF_QKV;   // 3 x [B,H,S,D] bf16
  ushort* ao  = ws + OFF_AO;    // [8192][768] bf16

  // input conversion + weight transposes
  cvt_bf16<<<dim3(3072), 256, 0, stream>>>(x, xb, 786432);
  transpose_w<<<dim3(12, 12), 256, 0, stream>>>(Wq, wt + 0 * 589824, 768, 64);
  transpose_w<<<dim3(12, 12), 256, 0, stream>>>(Wk, wt + 1 * 589824, 768, 64);
  transpose_w<<<dim3(12, 12), 256, 0, stream>>>(Wv, wt + 2 * 589824, 768, 64);
  transpose_w<<<dim3(144, 1), 256, 0, stream>>>(Wp, wpt, 768, 768);

  // QKV projection
  gemm_qkv<<<dim3(128, 36), 256, 0, stream>>>(xb, wt, qkv);

  // attention
  attn_fwd<<<dim3(32, 48), 256, 0, stream>>>(qkv, qkv + 6291456, qkv + 2 * 6291456, ao);

  // output projection
  gemm_out<<<dim3(128, 12), 256, 0, stream>>>(ao, wpt, bp, out);
}

// Round 3
// 226.992 us; speedup vs baseline: 1.2252x; 1.2252x over previous
//
#include <hip/hip_runtime.h>
#include <hip/hip_bf16.h>

// MultiHeadAttention: B=4 H=12 S=2048 D=64 E=768, causal. fp32 in/out, bf16 MFMA compute.
// R2: attn rebuilt on 32x32x16 MFMA, in-register P (cvt_pk + permlane32_swap),
//     KVBLK=64, wave=32 q-rows, conflict-free V^T staging. GEMMs: M-tile 128.

typedef __attribute__((ext_vector_type(8))) short bf16x8;
typedef __attribute__((ext_vector_type(4))) float f32x4;
typedef __attribute__((ext_vector_type(16))) float f32x16;
typedef __attribute__((ext_vector_type(4))) uint u32x4;

// ws offsets in bf16 elements
#define OFF_XB   0            // 8192*768            = 6291456
#define OFF_WT   6291456      // 3 * 12*64*768       = 1769472
#define OFF_WPT  8060928      // 768*768             =  589824
#define OFF_QKV  8650752      // 3 * 4*12*2048*64    = 18874368
#define OFF_AO   27525120     // 8192*768            = 6291456

#define SCALE_LOG2E 0.1803368801111204f   // (1/8) * log2(e)

__device__ inline ushort f2bf(float f) {
  __hip_bfloat16 h = __float2bfloat16(f);
  return *reinterpret_cast<ushort*>(&h);
}
__device__ inline uint cvt_pk(float lo, float hi) {
  uint r;
  asm("v_cvt_pk_bf16_f32 %0, %1, %2" : "=v"(r) : "v"(lo), "v"(hi));
  return r;
}

// ---------- fp32 -> bf16 bulk convert (8 elems/thread)
__global__ __launch_bounds__(256) void cvt_bf16(const float* __restrict__ src,
                                                ushort* __restrict__ dst, int n8) {
  int i = blockIdx.x * 256 + threadIdx.x;
  if (i >= n8) return;
  float4 a = *(const float4*)&src[(size_t)i * 8];
  float4 b = *(const float4*)&src[(size_t)i * 8 + 4];
  ushort u[8] = {f2bf(a.x), f2bf(a.y), f2bf(a.z), f2bf(a.w),
                 f2bf(b.x), f2bf(b.y), f2bf(b.z), f2bf(b.w)};
  *(bf16x8*)&dst[(size_t)i * 8] = *(bf16x8*)u;
}

// ---------- tiled 64x64 transpose+convert: fp32 [mat][Edim][Ddim] -> bf16 [mat][Ddim][Edim]
__global__ __launch_bounds__(256) void transpose_w(const float* __restrict__ src,
                                                   ushort* __restrict__ dst,
                                                   int Edim, int Ddim) {
  __shared__ ushort tile[64][130];
  int mat = blockIdx.y;
  int ntd = Ddim >> 6;
  int te = blockIdx.x / ntd, td = blockIdx.x % ntd;
  size_t base = (size_t)mat * Edim * Ddim;
  int t = threadIdx.x;
#pragma unroll
  for (int i = 0; i < 16; i++) {
    int idx = i * 256 + t;
    int r = idx >> 6, c = idx & 63;
    tile[r][c] = f2bf(src[base + (size_t)(te * 64 + r) * Ddim + td * 64 + c]);
  }
  __syncthreads();
#pragma unroll
  for (int i = 0; i < 16; i++) {
    int idx = i * 256 + t;
    int c = idx >> 6, r = idx & 63;
    dst[base + (size_t)(td * 64 + c) * Edim + te * 64 + r] = tile[r][c];
  }
}

// ---------- QKV projection GEMM: X[8192,768] @ Wt -> qkv bf16. grid (64, 36)
__global__ __launch_bounds__(256) void gemm_qkv(const ushort* __restrict__ X,
                                                const ushort* __restrict__ Wt,
                                                ushort* __restrict__ qkv) {
  __shared__ ushort Alds[128 * 40];
  __shared__ ushort Blds[64 * 40];
  int mb = blockIdx.x, nb = blockIdx.y;
  int t = threadIdx.x, w = t >> 6, lane = t & 63, lo = lane & 15, g = lane >> 4;
  const ushort* Wb = Wt + (size_t)nb * 49152;
  f32x4 acc[2][4];
#pragma unroll
  for (int qi = 0; qi < 2; qi++)
#pragma unroll
    for (int n = 0; n < 4; n++) acc[qi][n] = (f32x4){0.f, 0.f, 0.f, 0.f};
  int r = t >> 2, c4 = t & 3;
  for (int e0 = 0; e0 < 768; e0 += 32) {
#pragma unroll
    for (int i = 0; i < 2; i++)
      *(bf16x8*)&Alds[(i * 64 + r) * 40 + c4 * 8] =
          *(const bf16x8*)&X[(size_t)(mb * 128 + i * 64 + r) * 768 + e0 + c4 * 8];
    *(bf16x8*)&Blds[r * 40 + c4 * 8] =
        *(const bf16x8*)&Wb[(size_t)r * 768 + e0 + c4 * 8];
    __syncthreads();
    bf16x8 a0 = *(const bf16x8*)&Alds[(w * 32 + lo) * 40 + g * 8];
    bf16x8 a1 = *(const bf16x8*)&Alds[(w * 32 + 16 + lo) * 40 + g * 8];
#pragma unroll
    for (int n = 0; n < 4; n++) {
      bf16x8 b = *(const bf16x8*)&Blds[(n * 16 + lo) * 40 + g * 8];
      acc[0][n] = __builtin_amdgcn_mfma_f32_16x16x32_bf16(a0, b, acc[0][n], 0, 0, 0);
      acc[1][n] = __builtin_amdgcn_mfma_f32_16x16x32_bf16(a1, b, acc[1][n], 0, 0, 0);
    }
    __syncthreads();
  }
  int ty = nb / 12, h = nb % 12;
#pragma unroll
  for (int qi = 0; qi < 2; qi++)
#pragma unroll
    for (int n = 0; n < 4; n++) {
      int d = n * 16 + lo;
#pragma unroll
      for (int rr = 0; rr < 4; rr++) {
        int m = mb * 128 + w * 32 + qi * 16 + g * 4 + rr;
        int b = m >> 11, s = m & 2047;
        qkv[(size_t)ty * 6291456 + (size_t)(b * 12 + h) * 131072 + (size_t)s * 64 + d] =
            f2bf(acc[qi][n][rr]);
      }
    }
}

// ---------- causal flash attention, 32x32 MFMA, in-register P.
// grid: x = 32 (paired q-tiles of 64), y = 48 (b*12+h). 128 threads = 2 waves, wave = 32 q.
__global__ __launch_bounds__(128, 3) void attn_fwd(const ushort* __restrict__ Qg,
                                                   const ushort* __restrict__ Kg,
                                                   const ushort* __restrict__ Vg,
                                                   ushort* __restrict__ ao) {
  __shared__ ushort Klds[64 * 72];  // [kv 0..63][d 0..63], row stride 72 u (144 B)
  __shared__ uint Vt32[64 * 36];    // [d 0..63][kv-pair 0..31], row stride 36 words
  int x = blockIdx.x, bh = blockIdx.y;
  int qb = (x & 1) ? (x >> 1) : (31 - (x >> 1));  // pair heavy/light tiles
  int t = threadIdx.x, w = t >> 6, lane = t & 63, q31 = lane & 31, hi = lane >> 5;
  const ushort* Q = Qg + (size_t)bh * 131072;
  const ushort* K = Kg + (size_t)bh * 131072;
  const ushort* V = Vg + (size_t)bh * 131072;
  int q0 = qb * 64;
  int qg = q0 + w * 32 + q31;
  // Q B-fragments in registers: qf[step]: Q[qg][step*16 + hi*8 .. +7]
  bf16x8 qf[4];
#pragma unroll
  for (int s = 0; s < 4; s++)
    qf[s] = *(const bf16x8*)&Q[(size_t)qg * 64 + s * 16 + hi * 8];
  f32x16 oacc[2];
#pragma unroll
  for (int dt = 0; dt < 2; dt++)
#pragma unroll
    for (int r = 0; r < 16; r++) oacc[dt][r] = 0.f;
  float zrun = -1e30f, lrun = 0.f;
  int nkb = qb + 1;
  // staging mapping
  int vpr = t & 31;               // kv-pair 0..31
  int vdcb = t >> 5;              // 0..3; handles dc = vdcb and vdcb+4
  for (int kb = 0; kb < nkb; kb++) {
    int t0 = kb * 64;
    // --- stage K row-major [64][72]
#pragma unroll
    for (int i = 0; i < 4; i++) {
      int idx = i * 128 + t;
      int r = idx >> 3, c = idx & 7;
      *(bf16x8*)&Klds[r * 72 + c * 8] =
          *(const bf16x8*)&K[(size_t)(t0 + r) * 64 + c * 8];
    }
    // --- stage V transposed pair-packed: Vt32[d][pr] = (V[2pr][d], V[2pr+1][d])
#pragma unroll
    for (int dd = 0; dd < 2; dd++) {
      int dc = vdcb + dd * 4;
      bf16x8 va = *(const bf16x8*)&V[(size_t)(t0 + 2 * vpr) * 64 + dc * 8];
      bf16x8 vb = *(const bf16x8*)&V[(size_t)(t0 + 2 * vpr + 1) * 64 + dc * 8];
#pragma unroll
      for (int i = 0; i < 8; i++) {
        uint val = (uint)(ushort)va[i] | ((uint)(ushort)vb[i] << 16);
        Vt32[(dc * 8 + i) * 36 + vpr] = val;
      }
    }
    __syncthreads();
    bool diag = (kb == nkb - 1);
    // --- QK^T (swapped): st[kvt] = K_tile * Q^T -> S^T[kv][q], col q = q31
    f32x16 st[2];
#pragma unroll
    for (int kvt = 0; kvt < 2; kvt++)
#pragma unroll
      for (int r = 0; r < 16; r++) st[kvt][r] = 0.f;
#pragma unroll
    for (int kvt = 0; kvt < 2; kvt++) {
      if (!diag || kvt <= w) {
#pragma unroll
        for (int s = 0; s < 4; s++) {
          bf16x8 kf = *(const bf16x8*)&Klds[(kvt * 32 + q31) * 72 + s * 16 + hi * 8];
          st[kvt] = __builtin_amdgcn_mfma_f32_32x32x16_bf16(kf, qf[s], st[kvt], 0, 0, 0);
        }
      }
    }
    // --- scale to log2 domain, causal mask, tile max
    float z[32];
    float zmax = -1e30f;
#pragma unroll
    for (int kvt = 0; kvt < 2; kvt++)
#pragma unroll
      for (int r = 0; r < 16; r++) {
        float zz = st[kvt][r] * SCALE_LOG2E;
        if (diag) {
          int kvg = t0 + kvt * 32 + (r & 3) + 8 * (r >> 2) + 4 * hi;
          zz = (kvg <= qg) ? zz : -1e30f;
        }
        z[kvt * 16 + r] = zz;
        zmax = fmaxf(zmax, zz);
      }
    zmax = fmaxf(zmax, __shfl_xor(zmax, 32));
    float znew = fmaxf(zrun, zmax);
    float sf = exp2f(zrun - znew);
    zrun = znew;
    float ts = 0.f;
#pragma unroll
    for (int i = 0; i < 32; i++) {
      z[i] = exp2f(z[i] - znew);
      ts += z[i];
    }
    ts += __shfl_xor(ts, 32);
    lrun = lrun * sf + ts;
    // --- pack P to bf16 A-frags: per 16-kv window: 4 cvt_pk + 2 permlane32_swap
    bf16x8 paf[4];
#pragma unroll
    for (int s = 0; s < 4; s++) {
      int rb = s * 8;  // z index base: kvt*16 + w16*8 == s*8
      uint a = cvt_pk(z[rb + 0], z[rb + 1]);
      uint b2 = cvt_pk(z[rb + 2], z[rb + 3]);
      uint c = cvt_pk(z[rb + 4], z[rb + 5]);
      uint d = cvt_pk(z[rb + 6], z[rb + 7]);
      asm volatile("v_permlane32_swap_b32 %0, %1" : "+v"(a), "+v"(c));
      asm volatile("v_permlane32_swap_b32 %0, %1" : "+v"(b2), "+v"(d));
      u32x4 u4 = {a, b2, c, d};
      paf[s] = __builtin_bit_cast(bf16x8, u4);
    }
    // --- rescale O accumulators (row q' = (r&3)+8*(r>>2)+4*hi)
    float sfr[16];
#pragma unroll
    for (int r = 0; r < 16; r++) sfr[r] = __shfl(sf, (r & 3) + 8 * (r >> 2) + 4 * hi);
#pragma unroll
    for (int dt = 0; dt < 2; dt++)
#pragma unroll
      for (int r = 0; r < 16; r++) oacc[dt][r] *= sfr[r];
    // --- PV: oacc[dt] += P * V
#pragma unroll
    for (int s = 0; s < 4; s++) {
#pragma unroll
      for (int dt = 0; dt < 2; dt++) {
        bf16x8 vf = *(const bf16x8*)&Vt32[(dt * 32 + q31) * 36 + s * 8 + hi * 4];
        oacc[dt] = __builtin_amdgcn_mfma_f32_32x32x16_bf16(paf[s], vf, oacc[dt], 0, 0, 0);
      }
    }
    __syncthreads();
  }
  // --- epilogue: normalize, write [B,S,H*D] bf16
  float li[16];
#pragma unroll
  for (int r = 0; r < 16; r++)
    li[r] = 1.f / __shfl(lrun, (r & 3) + 8 * (r >> 2) + 4 * hi);
  int hh = bh % 12, bb = bh / 12;
#pragma unroll
  for (int dt = 0; dt < 2; dt++)
#pragma unroll
    for (int r = 0; r < 16; r++) {
      int qr = q0 + w * 32 + (r & 3) + 8 * (r >> 2) + 4 * hi;
      ao[(size_t)(bb * 2048 + qr) * 768 + hh * 64 + dt * 32 + q31] =
          f2bf(oacc[dt][r] * li[r]);
    }
}

// ---------- output projection: ao[8192,768] @ Wp[768,768] + bp -> out fp32. grid (64, 12)
__global__ __launch_bounds__(256) void gemm_out(const ushort* __restrict__ A,
                                                const ushort* __restrict__ Bt,
                                                const float* __restrict__ bias,
                                                float* __restrict__ out) {
  __shared__ ushort Alds[128 * 40];
  __shared__ ushort Blds[64 * 40];
  int mb = blockIdx.x, nb = blockIdx.y;
  int t = threadIdx.x, w = t >> 6, lane = t & 63, lo = lane & 15, g = lane >> 4;
  const ushort* Bb = Bt + (size_t)nb * 49152;
  f32x4 acc[2][4];
#pragma unroll
  for (int qi = 0; qi < 2; qi++)
#pragma unroll
    for (int n = 0; n < 4; n++) acc[qi][n] = (f32x4){0.f, 0.f, 0.f, 0.f};
  int r = t >> 2, c4 = t & 3;
  for (int e0 = 0; e0 < 768; e0 += 32) {
#pragma unroll
    for (int i = 0; i < 2; i++)
      *(bf16x8*)&Alds[(i * 64 + r) * 40 + c4 * 8] =
          *(const bf16x8*)&A[(size_t)(mb * 128 + i * 64 + r) * 768 + e0 + c4 * 8];
    *(bf16x8*)&Blds[r * 40 + c4 * 8] =
        *(const bf16x8*)&Bb[(size_t)r * 768 + e0 + c4 * 8];
    __syncthreads();
    bf16x8 a0 = *(const bf16x8*)&Alds[(w * 32 + lo) * 40 + g * 8];
    bf16x8 a1 = *(const bf16x8*)&Alds[(w * 32 + 16 + lo) * 40 + g * 8];
#pragma unroll
    for (int n = 0; n < 4; n++) {
      bf16x8 b = *(const bf16x8*)&Blds[(n * 16 + lo) * 40 + g * 8];
      acc[0][n] = __builtin_amdgcn_mfma_f32_16x16x32_bf16(a0, b, acc[0][n], 0, 0, 0);
      acc[1][n] = __builtin_amdgcn_mfma_f32_16x16x32_bf16(a1, b, acc[1][n], 0, 0, 0);
    }
    __syncthreads();
  }
#pragma unroll
  for (int qi = 0; qi < 2; qi++)
#pragma unroll
    for (int n = 0; n < 4; n++) {
      int col = nb * 64 + n * 16 + lo;
      float bv = bias[col];
#pragma unroll
      for (int rr = 0; rr < 4; rr++) {
        int m = mb * 128 + w * 32 + qi * 16 + g * 4 + rr;
        out[(size_t)m * 768 + col] = acc[qi][n][rr] + bv;
      }
    }
}

extern "C" void kernel_launch(void* const* d_in, const int* in_sizes, int n_in,
                              void* d_out, int out_size, void* d_ws, size_t ws_size,
                              hipStream_t stream) {
  const float* x  = (const float*)d_in[0];
  const float* Wq = (const float*)d_in[1];
  const float* Wk = (const float*)d_in[2];
  const float* Wv = (const float*)d_in[3];
  const float* Wp = (const float*)d_in[4];
  const float* bp = (const float*)d_in[5];
  float* out = (float*)d_out;
  ushort* ws = (ushort*)d_ws;

  ushort* xb  = ws + OFF_XB;
  ushort* wt  = ws + OFF_WT;
  ushort* wpt = ws + OFF_WPT;
  ushort* qkv = ws + OFF_QKV;
  ushort* ao  = ws + OFF_AO;

  cvt_bf16<<<dim3(3072), 256, 0, stream>>>(x, xb, 786432);
  transpose_w<<<dim3(12, 12), 256, 0, stream>>>(Wq, wt + 0 * 589824, 768, 64);
  transpose_w<<<dim3(12, 12), 256, 0, stream>>>(Wk, wt + 1 * 589824, 768, 64);
  transpose_w<<<dim3(12, 12), 256, 0, stream>>>(Wv, wt + 2 * 589824, 768, 64);
  transpose_w<<<dim3(144, 1), 256, 0, stream>>>(Wp, wpt, 768, 768);

  gemm_qkv<<<dim3(64, 36), 256, 0, stream>>>(xb, wt, qkv);
  attn_fwd<<<dim3(32, 48), 128, 0, stream>>>(qkv, qkv + 6291456, qkv + 2 * 6291456, ao);
  gemm_out<<<dim3(64, 12), 256, 0, stream>>>(ao, wpt, bp, out);
}